// Round 1
// baseline (498.005 us; speedup 1.0000x reference)
//
#include <hip/hip_runtime.h>

typedef __bf16 bf16;
typedef __bf16 bf16x8 __attribute__((ext_vector_type(8)));
typedef float f32x4 __attribute__((ext_vector_type(4)));

// ---------------------------------------------------------------------------
// Weight prep: convert f32 W[K][N] into MFMA B-fragment-ordered bf16:
// dst[((kt*NT+nt)*64 + lane)*8 + j] = W[(kt*32 + (lane>>4)*8 + j)][nt*16 + (lane&15)]
// so the GEMM kernel can ds_read_b128 one fragment per lane.
// ---------------------------------------------------------------------------
__global__ __launch_bounds__(256) void wprep(const float* __restrict__ W,
                                             bf16* __restrict__ dst, int K, int N) {
  int idx = blockIdx.x * 256 + threadIdx.x;          // one thread = one (frag, lane)
  int total = (K / 32) * (N / 16) * 64;
  if (idx >= total) return;
  int lane = idx & 63;
  int fi = idx >> 6;
  int NT = N / 16;
  int kt = fi / NT, nt = fi % NT;
  int krow = kt * 32 + ((lane >> 4) << 3);
  int col = nt * 16 + (lane & 15);
  bf16* d = dst + (size_t)idx * 8;
#pragma unroll
  for (int j = 0; j < 8; ++j) d[j] = (bf16)W[(size_t)(krow + j) * N + col];
}

// ---------------------------------------------------------------------------
// Generic tall-skinny GEMM:  out[M][N] = act(A[M][K] @ W + b)  (opt. l2norm)
// ---------------------------------------------------------------------------
struct GemmArgs {
  const void* a0; const void* a1; const void* a2; const void* a3; const void* a4;
  const int* bidx; const int* sidx;
  const bf16* wfrag; const float* bias;
  void* out; int M;
};

__device__ inline bf16x8 cvt8(const float* p) {
  const f32x4* q = (const f32x4*)p;
  f32x4 x0 = q[0];
  f32x4 x1 = q[1];
  bf16x8 a;
  a[0] = (bf16)x0[0]; a[1] = (bf16)x0[1]; a[2] = (bf16)x0[2]; a[3] = (bf16)x0[3];
  a[4] = (bf16)x1[0]; a[5] = (bf16)x1[1]; a[6] = (bf16)x1[2]; a[7] = (bf16)x1[3];
  return a;
}

// ASRC: 0 = contiguous f32 [M][K], 1 = contiguous bf16 [M][K],
//       2 = item concat (tire|brand[idx]|size[idx]|specs|text_proj),
//       3 = user concat (h_user|pool)
template <int K, int ASRC>
__device__ inline bf16x8 load_a(const GemmArgs& g, int r, int kc) {
  if constexpr (ASRC == 0) {
    return cvt8((const float*)g.a0 + (size_t)r * K + kc);
  } else if constexpr (ASRC == 1) {
    return *(const bf16x8*)((const bf16*)g.a0 + (size_t)r * K + kc);
  } else if constexpr (ASRC == 2) {
    if (kc < 128) {                              // h_tire [T][128] f32
      return cvt8((const float*)g.a0 + (size_t)r * 128 + kc);
    } else if (kc < 256) {                       // h_brand[bidx[r]] f32
      int bi = g.bidx[r];
      return cvt8((const float*)g.a1 + (size_t)bi * 128 + (kc - 128));
    } else if (kc < 384) {                       // h_size[sidx[r]] f32
      int si = g.sidx[r];
      return cvt8((const float*)g.a2 + (size_t)si * 128 + (kc - 256));
    } else if (kc < 448) {                       // specs [T][64] f32
      return cvt8((const float*)g.a3 + (size_t)r * 64 + (kc - 384));
    } else {                                     // text_proj [T][64] bf16
      return *(const bf16x8*)((const bf16*)g.a4 + (size_t)r * 64 + (kc - 448));
    }
  } else {
    if (kc < 128) {                              // h_user [U][128] f32
      return cvt8((const float*)g.a0 + (size_t)r * 128 + kc);
    } else {                                     // pool [U][64] bf16
      return *(const bf16x8*)((const bf16*)g.a1 + (size_t)r * 64 + (kc - 128));
    }
  }
}

template <int K, int N, int ASRC, int RELU, int L2N>
__global__ __launch_bounds__(256) void gemm_k(GemmArgs g) {
  constexpr int KT = K / 32, NT = N / 16;
  __shared__ bf16 wlds[K * N];                   // fragment-ordered weights
  {
    const uint4* s = (const uint4*)g.wfrag;
    uint4* d = (uint4*)wlds;
    constexpr int CH = K * N * 2 / 16;
    for (int i = threadIdx.x; i < CH; i += 256) d[i] = s[i];
  }
  __syncthreads();

  const int lane = threadIdx.x & 63;
  const int wave = threadIdx.x >> 6;
  const int kgo = (lane >> 4) << 3;              // this lane-group's k offset
  const int ntiles = (g.M + 127) >> 7;           // 128 rows per block

  for (int tile = blockIdx.x; tile < ntiles; tile += gridDim.x) {
    const int rowbase = tile << 7;
    const int rw = rowbase + wave * 16 + (lane & 15);
    const int r0 = min(rw, g.M - 1);             // clamp: OOB rows read row M-1,
    const int r1 = min(rw + 64, g.M - 1);        // stores are guarded below

    f32x4 acc[2][NT] = {};

#pragma unroll 2
    for (int kt = 0; kt < KT; ++kt) {
      const int kc = kt * 32 + kgo;
      bf16x8 a0 = load_a<K, ASRC>(g, r0, kc);
      bf16x8 a1 = load_a<K, ASRC>(g, r1, kc);
      const bf16x8* bp = ((const bf16x8*)wlds) + kt * NT * 64 + lane;
#pragma unroll
      for (int nt = 0; nt < NT; ++nt) {
        bf16x8 b = bp[nt * 64];
        acc[0][nt] = __builtin_amdgcn_mfma_f32_16x16x32_bf16(a0, b, acc[0][nt], 0, 0, 0);
        acc[1][nt] = __builtin_amdgcn_mfma_f32_16x16x32_bf16(a1, b, acc[1][nt], 0, 0, 0);
      }
    }

    // Epilogue. D layout: col = lane&15 (+16*nt), row = (lane>>4)*4 + j
    const int colbase = lane & 15;
    const int rgrp = (lane >> 4) * 4;
#pragma unroll
    for (int m = 0; m < 2; ++m) {
      const int rbase = rowbase + m * 64 + wave * 16 + rgrp;
#pragma unroll
      for (int nt = 0; nt < NT; ++nt) {
        const float bv = g.bias[colbase + nt * 16];
        f32x4 dv = acc[m][nt];
#pragma unroll
        for (int j = 0; j < 4; ++j) {
          float v = dv[j] + bv;
          if constexpr (RELU != 0) v = fmaxf(v, 0.0f);
          dv[j] = v;
        }
        acc[m][nt] = dv;
      }
      if constexpr (L2N != 0) {
#pragma unroll
        for (int j = 0; j < 4; ++j) {
          float ssq = 0.0f;
#pragma unroll
          for (int nt = 0; nt < NT; ++nt) ssq += acc[m][nt][j] * acc[m][nt][j];
          ssq += __shfl_xor(ssq, 1);             // reduce across the 16-lane group
          ssq += __shfl_xor(ssq, 2);             // (covers all 64 cols of the row)
          ssq += __shfl_xor(ssq, 4);
          ssq += __shfl_xor(ssq, 8);
          const float scale = 1.0f / fmaxf(sqrtf(ssq), 1e-12f);
          const int r = rbase + j;
          if (r < g.M) {
            float* o = (float*)g.out + (size_t)r * N + colbase;
#pragma unroll
            for (int nt = 0; nt < NT; ++nt) o[nt * 16] = acc[m][nt][j] * scale;
          }
        }
      } else {
#pragma unroll
        for (int j = 0; j < 4; ++j) {
          const int r = rbase + j;
          if (r < g.M) {
            bf16* o = (bf16*)g.out + (size_t)r * N + colbase;
#pragma unroll
            for (int nt = 0; nt < NT; ++nt) o[nt * 16] = (bf16)acc[m][nt][j];
          }
        }
      }
    }
  }
}

// ---------------------------------------------------------------------------
// Segment-mean pooling: one wave per user, binary search on sorted segments,
// then mean of item_vec rows. Writes pool[U][64] bf16.
// ---------------------------------------------------------------------------
__global__ __launch_bounds__(256) void pool_k(const int* __restrict__ hitems,
                                              const int* __restrict__ hsegs, int E,
                                              const float* __restrict__ itemvec,
                                              bf16* __restrict__ pool, int U) {
  const int lane = threadIdx.x & 63;
  const int wave = blockIdx.x * 4 + (threadIdx.x >> 6);
  const int stride = gridDim.x * 4;
  for (int u = wave; u < U; u += stride) {
    int lo = 0, hi = E;
    while (lo < hi) { int mid = (lo + hi) >> 1; if (hsegs[mid] < u) lo = mid + 1; else hi = mid; }
    const int s = lo;
    hi = E;
    while (lo < hi) { int mid = (lo + hi) >> 1; if (hsegs[mid] < u + 1) lo = mid + 1; else hi = mid; }
    const int e = lo;

    float sum = 0.0f;
    int i = s;
    for (; i + 4 <= e; i += 4) {
      int i0 = hitems[i], i1 = hitems[i + 1], i2 = hitems[i + 2], i3 = hitems[i + 3];
      float v0 = itemvec[(size_t)i0 * 64 + lane];
      float v1 = itemvec[(size_t)i1 * 64 + lane];
      float v2 = itemvec[(size_t)i2 * 64 + lane];
      float v3 = itemvec[(size_t)i3 * 64 + lane];
      sum += (v0 + v1) + (v2 + v3);
    }
    for (; i < e; ++i) {
      int it = hitems[i];
      sum += itemvec[(size_t)it * 64 + lane];
    }
    const float cnt = (float)(e - s);
    const float v = (e > s) ? sum / cnt : 0.0f;
    pool[(size_t)u * 64 + lane] = (bf16)v;
  }
}

// ---------------------------------------------------------------------------
extern "C" void kernel_launch(void* const* d_in, const int* in_sizes, int n_in,
                              void* d_out, int out_size, void* d_ws, size_t ws_size,
                              hipStream_t stream) {
  const float* h_user = (const float*)d_in[0];
  const float* h_tire = (const float*)d_in[1];
  const float* h_brand = (const float*)d_in[2];
  const float* h_size = (const float*)d_in[3];
  const float* specs = (const float*)d_in[4];
  const float* text = (const float*)d_in[5];
  const int* bidx = (const int*)d_in[6];
  const int* sidx = (const int*)d_in[7];
  const int* hitems = (const int*)d_in[8];
  const int* hsegs = (const int*)d_in[9];
  const float* W_tp = (const float*)d_in[10]; const float* b_tp = (const float*)d_in[11];
  const float* W_i1 = (const float*)d_in[12]; const float* b_i1 = (const float*)d_in[13];
  const float* W_i2 = (const float*)d_in[14]; const float* b_i2 = (const float*)d_in[15];
  const float* W_i3 = (const float*)d_in[16]; const float* b_i3 = (const float*)d_in[17];
  const float* W_u1 = (const float*)d_in[18]; const float* b_u1 = (const float*)d_in[19];
  const float* W_u2 = (const float*)d_in[20]; const float* b_u2 = (const float*)d_in[21];
  const float* W_u3 = (const float*)d_in[22]; const float* b_u3 = (const float*)d_in[23];

  const int U = in_sizes[0] / 128;   // 100000
  const int T = in_sizes[4] / 64;    // 100000
  const int E = in_sizes[8];         // 2000000

  // workspace layout (~77 MB total)
  char* ws = (char*)d_ws;
  size_t off = 0;
  auto alloc = [&](size_t bytes) -> char* {
    char* p = ws + off;
    off += (bytes + 255) & ~(size_t)255;
    return p;
  };
  bf16* wf_tp = (bf16*)alloc(384 * 64 * 2);
  bf16* wf_i1 = (bf16*)alloc(512 * 128 * 2);
  bf16* wf_i2 = (bf16*)alloc(128 * 128 * 2);
  bf16* wf_i3 = (bf16*)alloc(128 * 64 * 2);
  bf16* wf_u1 = (bf16*)alloc(192 * 128 * 2);
  bf16* wf_u2 = (bf16*)alloc(128 * 128 * 2);
  bf16* wf_u3 = (bf16*)alloc(128 * 64 * 2);
  bf16* tpbuf = (bf16*)alloc((size_t)T * 64 * 2);
  bf16* h1 = (bf16*)alloc((size_t)T * 128 * 2);
  bf16* h2 = (bf16*)alloc((size_t)T * 128 * 2);
  bf16* pool = (bf16*)alloc((size_t)U * 64 * 2);
  (void)ws_size; (void)n_in; (void)out_size;

  auto wp = [&](const float* W, bf16* dst, int K, int N) {
    int total = K * N / 8;
    wprep<<<(total + 255) / 256, 256, 0, stream>>>(W, dst, K, N);
  };
  wp(W_tp, wf_tp, 384, 64);
  wp(W_i1, wf_i1, 512, 128);
  wp(W_i2, wf_i2, 128, 128);
  wp(W_i3, wf_i3, 128, 64);
  wp(W_u1, wf_u1, 192, 128);
  wp(W_u2, wf_u2, 128, 128);
  wp(W_u3, wf_u3, 128, 64);

  float* out_user = (float*)d_out;
  float* out_item = out_user + (size_t)U * 64;

  const int tilesT = (T + 127) / 128;
  const int tilesU = (U + 127) / 128;

  {  // text projection: [T,384] f32 @ [384,64] -> relu -> tpbuf bf16
    GemmArgs a = {}; a.a0 = text; a.wfrag = wf_tp; a.bias = b_tp; a.out = tpbuf; a.M = T;
    gemm_k<384, 64, 0, 1, 0><<<tilesT, 256, 0, stream>>>(a);
  }
  {  // item L1: concat-512 @ [512,128] -> relu -> h1   (128KB LDS: grid=1 block/CU)
    GemmArgs a = {}; a.a0 = h_tire; a.a1 = h_brand; a.a2 = h_size; a.a3 = specs; a.a4 = tpbuf;
    a.bidx = bidx; a.sidx = sidx; a.wfrag = wf_i1; a.bias = b_i1; a.out = h1; a.M = T;
    gemm_k<512, 128, 2, 1, 0><<<256, 256, 0, stream>>>(a);
  }
  {  // item L2
    GemmArgs a = {}; a.a0 = h1; a.wfrag = wf_i2; a.bias = b_i2; a.out = h2; a.M = T;
    gemm_k<128, 128, 1, 1, 0><<<tilesT, 256, 0, stream>>>(a);
  }
  {  // item L3 + l2norm -> d_out item section (f32)
    GemmArgs a = {}; a.a0 = h2; a.wfrag = wf_i3; a.bias = b_i3; a.out = out_item; a.M = T;
    gemm_k<128, 64, 1, 0, 1><<<tilesT, 256, 0, stream>>>(a);
  }
  // history mean-pool (reads item vectors just written to d_out)
  pool_k<<<(U + 3) / 4, 256, 0, stream>>>(hitems, hsegs, E, out_item, pool, U);
  {  // user L1: concat-192 @ [192,128] -> relu -> h1
    GemmArgs a = {}; a.a0 = h_user; a.a1 = pool; a.wfrag = wf_u1; a.bias = b_u1; a.out = h1; a.M = U;
    gemm_k<192, 128, 3, 1, 0><<<tilesU, 256, 0, stream>>>(a);
  }
  {  // user L2
    GemmArgs a = {}; a.a0 = h1; a.wfrag = wf_u2; a.bias = b_u2; a.out = h2; a.M = U;
    gemm_k<128, 128, 1, 1, 0><<<tilesU, 256, 0, stream>>>(a);
  }
  {  // user L3 + l2norm -> d_out user section (f32)
    GemmArgs a = {}; a.a0 = h2; a.wfrag = wf_u3; a.bias = b_u3; a.out = out_user; a.M = U;
    gemm_k<128, 64, 1, 0, 1><<<tilesU, 256, 0, stream>>>(a);
  }
}

// Round 2
// 286.640 us; speedup vs baseline: 1.7374x; 1.7374x over previous
//
#include <hip/hip_runtime.h>

typedef __bf16 bf16;
typedef __bf16 bf16x4 __attribute__((ext_vector_type(4)));
typedef __bf16 bf16x8 __attribute__((ext_vector_type(8)));
typedef float f32x4 __attribute__((ext_vector_type(4)));

__device__ inline float bfbits(unsigned u) { return __builtin_bit_cast(float, u); }

// ---------------------------------------------------------------------------
// Weight prep: convert f32 W[K][N] into MFMA B-fragment-ordered bf16:
// dst[((kt*NT+nt)*64 + lane)*8 + j] = W[(kt*32 + (lane>>4)*8 + j)][nt*16 + (lane&15)]
// ---------------------------------------------------------------------------
__global__ __launch_bounds__(256) void wprep(const float* __restrict__ W,
                                             bf16* __restrict__ dst, int K, int N) {
  int idx = blockIdx.x * 256 + threadIdx.x;
  int total = (K / 32) * (N / 16) * 64;
  if (idx >= total) return;
  int lane = idx & 63;
  int fi = idx >> 6;
  int NT = N / 16;
  int kt = fi / NT, nt = fi % NT;
  int krow = kt * 32 + ((lane >> 4) << 3);
  int col = nt * 16 + (lane & 15);
  bf16* d = dst + (size_t)idx * 8;
#pragma unroll
  for (int j = 0; j < 8; ++j) d[j] = (bf16)W[(size_t)(krow + j) * N + col];
}

// ---------------------------------------------------------------------------
// Segment bounds: bound[u] = first index i with hsegs[i] >= u, for u in [0,U].
// One streaming pass over the sorted hsegs (replaces per-wave binary search).
// ---------------------------------------------------------------------------
__global__ __launch_bounds__(256) void seg_bounds(const int* __restrict__ hsegs,
                                                  int* __restrict__ bound, int E, int U) {
  int e = blockIdx.x * 256 + threadIdx.x;
  if (e > E) return;
  if (e == 0) {
    int b = hsegs[0];
    for (int u = 0; u <= b; ++u) bound[u] = 0;
  } else if (e == E) {
    int a = hsegs[E - 1];
    for (int u = a + 1; u <= U; ++u) bound[u] = E;
  } else {
    int a = hsegs[e - 1], b = hsegs[e];
    for (int u = a + 1; u <= b; ++u) bound[u] = e;
  }
}

// ---------------------------------------------------------------------------
// Generic tall-skinny GEMM:  out[M][N] = act(A[M][K] @ W + b)  (opt. l2norm)
// ---------------------------------------------------------------------------
struct GemmArgs {
  const void* a0; const void* a1; const void* a2; const void* a3; const void* a4;
  const int* bidx; const int* sidx;
  const bf16* wfrag; const float* bias;
  void* out; void* out2; int M;
};

__device__ inline bf16x8 cvt8(const float* p) {
  const f32x4* q = (const f32x4*)p;
  f32x4 x0 = q[0];
  f32x4 x1 = q[1];
  bf16x8 a;
  a[0] = (bf16)x0[0]; a[1] = (bf16)x0[1]; a[2] = (bf16)x0[2]; a[3] = (bf16)x0[3];
  a[4] = (bf16)x1[0]; a[5] = (bf16)x1[1]; a[6] = (bf16)x1[2]; a[7] = (bf16)x1[3];
  return a;
}

// ASRC: 0 = contiguous f32 [M][K], 1 = contiguous bf16 [M][K],
//       2 = item concat (tire|brand[idx]|size[idx]|specs|text_proj),
//       3 = user concat (h_user|pool)
template <int K, int ASRC>
__device__ inline bf16x8 load_a(const GemmArgs& g, int r, int kc) {
  if constexpr (ASRC == 0) {
    return cvt8((const float*)g.a0 + (size_t)r * K + kc);
  } else if constexpr (ASRC == 1) {
    return *(const bf16x8*)((const bf16*)g.a0 + (size_t)r * K + kc);
  } else if constexpr (ASRC == 2) {
    if (kc < 128) {
      return cvt8((const float*)g.a0 + (size_t)r * 128 + kc);
    } else if (kc < 256) {
      int bi = g.bidx[r];
      return cvt8((const float*)g.a1 + (size_t)bi * 128 + (kc - 128));
    } else if (kc < 384) {
      int si = g.sidx[r];
      return cvt8((const float*)g.a2 + (size_t)si * 128 + (kc - 256));
    } else if (kc < 448) {
      return cvt8((const float*)g.a3 + (size_t)r * 64 + (kc - 384));
    } else {
      return *(const bf16x8*)((const bf16*)g.a4 + (size_t)r * 64 + (kc - 448));
    }
  } else {
    if (kc < 128) {
      return cvt8((const float*)g.a0 + (size_t)r * 128 + kc);
    } else {
      return *(const bf16x8*)((const bf16*)g.a1 + (size_t)r * 64 + (kc - 128));
    }
  }
}

// NW = waves per block; tile = NW*32 rows (each wave owns 2 row-groups of 16).
template <int K, int N, int ASRC, int RELU, int L2N, int NW>
__global__ __launch_bounds__(NW * 64) void gemm_k(GemmArgs g) {
  constexpr int KT = K / 32, NT = N / 16;
  constexpr int TROWS = NW * 32;
  __shared__ bf16 wlds[K * N];
  {
    const uint4* s = (const uint4*)g.wfrag;
    uint4* d = (uint4*)wlds;
    constexpr int CH = K * N * 2 / 16;
    for (int i = threadIdx.x; i < CH; i += NW * 64) d[i] = s[i];
  }
  __syncthreads();

  const int lane = threadIdx.x & 63;
  const int wave = threadIdx.x >> 6;
  const int kgo = (lane >> 4) << 3;
  const int ntiles = (g.M + TROWS - 1) / TROWS;

  for (int tile = blockIdx.x; tile < ntiles; tile += gridDim.x) {
    const int rowbase = tile * TROWS;
    const int rw = rowbase + wave * 16 + (lane & 15);
    const int r0 = min(rw, g.M - 1);
    const int r1 = min(rw + NW * 16, g.M - 1);

    f32x4 acc[2][NT] = {};

#pragma unroll 2
    for (int kt = 0; kt < KT; ++kt) {
      const int kc = kt * 32 + kgo;
      bf16x8 a0 = load_a<K, ASRC>(g, r0, kc);
      bf16x8 a1 = load_a<K, ASRC>(g, r1, kc);
      const bf16x8* bp = ((const bf16x8*)wlds) + kt * NT * 64 + lane;
#pragma unroll
      for (int nt = 0; nt < NT; ++nt) {
        bf16x8 b = bp[nt * 64];
        acc[0][nt] = __builtin_amdgcn_mfma_f32_16x16x32_bf16(a0, b, acc[0][nt], 0, 0, 0);
        acc[1][nt] = __builtin_amdgcn_mfma_f32_16x16x32_bf16(a1, b, acc[1][nt], 0, 0, 0);
      }
    }

    // Epilogue. D layout: col = lane&15 (+16*nt), row = (lane>>4)*4 + j
    const int colbase = lane & 15;
    const int rgrp = (lane >> 4) * 4;
#pragma unroll
    for (int m = 0; m < 2; ++m) {
      const int rbase = rowbase + m * (NW * 16) + wave * 16 + rgrp;
#pragma unroll
      for (int nt = 0; nt < NT; ++nt) {
        const float bv = g.bias[colbase + nt * 16];
        f32x4 dv = acc[m][nt];
#pragma unroll
        for (int j = 0; j < 4; ++j) {
          float v = dv[j] + bv;
          if constexpr (RELU != 0) v = fmaxf(v, 0.0f);
          dv[j] = v;
        }
        acc[m][nt] = dv;
      }
      if constexpr (L2N != 0) {
#pragma unroll
        for (int j = 0; j < 4; ++j) {
          float ssq = 0.0f;
#pragma unroll
          for (int nt = 0; nt < NT; ++nt) ssq += acc[m][nt][j] * acc[m][nt][j];
          ssq += __shfl_xor(ssq, 1);
          ssq += __shfl_xor(ssq, 2);
          ssq += __shfl_xor(ssq, 4);
          ssq += __shfl_xor(ssq, 8);
          const float scale = 1.0f / fmaxf(sqrtf(ssq), 1e-12f);
          const int r = rbase + j;
          if (r < g.M) {
            float* o = (float*)g.out + (size_t)r * N + colbase;
#pragma unroll
            for (int nt = 0; nt < NT; ++nt) o[nt * 16] = acc[m][nt][j] * scale;
            if (g.out2) {
              bf16* o2 = (bf16*)g.out2 + (size_t)r * N + colbase;
#pragma unroll
              for (int nt = 0; nt < NT; ++nt) o2[nt * 16] = (bf16)(acc[m][nt][j] * scale);
            }
          }
        }
      } else {
#pragma unroll
        for (int j = 0; j < 4; ++j) {
          const int r = rbase + j;
          if (r < g.M) {
            bf16* o = (bf16*)g.out + (size_t)r * N + colbase;
#pragma unroll
            for (int nt = 0; nt < NT; ++nt) o[nt * 16] = (bf16)acc[m][nt][j];
          }
        }
      }
    }
  }
}

// ---------------------------------------------------------------------------
// Segment-mean pooling: one wave per user; precomputed bounds; bf16 item rows.
// Quarter-wave layout: 4 events/iter, each 16-lane group loads one 128B row
// (8 B per lane = 4 dims), unroll-2 for 8 concurrent gather chains.
// ---------------------------------------------------------------------------
__global__ __launch_bounds__(256) void pool_k(const int* __restrict__ hitems,
                                              const int* __restrict__ bound,
                                              const bf16* __restrict__ itemb,
                                              bf16* __restrict__ pool, int U) {
  const int lane = threadIdx.x & 63;
  const int wid = blockIdx.x * 4 + (threadIdx.x >> 6);
  const int stride = gridDim.x * 4;
  const int grp = lane >> 4, li = lane & 15;
  for (int u = wid; u < U; u += stride) {
    const int s = bound[u], e = bound[u + 1];
    f32x4 sa = {0.f, 0.f, 0.f, 0.f}, sb = {0.f, 0.f, 0.f, 0.f};
    int i = s + grp;
    for (; i + 4 < e; i += 8) {
      int it0 = hitems[i];
      int it1 = hitems[i + 4];
      uint2 r0 = *(const uint2*)(itemb + (size_t)it0 * 64 + li * 4);
      uint2 r1 = *(const uint2*)(itemb + (size_t)it1 * 64 + li * 4);
      sa[0] += bfbits(r0.x << 16);      sa[1] += bfbits(r0.x & 0xffff0000u);
      sa[2] += bfbits(r0.y << 16);      sa[3] += bfbits(r0.y & 0xffff0000u);
      sb[0] += bfbits(r1.x << 16);      sb[1] += bfbits(r1.x & 0xffff0000u);
      sb[2] += bfbits(r1.y << 16);      sb[3] += bfbits(r1.y & 0xffff0000u);
    }
    if (i < e) {
      int it0 = hitems[i];
      uint2 r0 = *(const uint2*)(itemb + (size_t)it0 * 64 + li * 4);
      sa[0] += bfbits(r0.x << 16);      sa[1] += bfbits(r0.x & 0xffff0000u);
      sa[2] += bfbits(r0.y << 16);      sa[3] += bfbits(r0.y & 0xffff0000u);
    }
#pragma unroll
    for (int c = 0; c < 4; ++c) sa[c] += sb[c];
#pragma unroll
    for (int c = 0; c < 4; ++c) {
      sa[c] += __shfl_xor(sa[c], 16);
      sa[c] += __shfl_xor(sa[c], 32);
    }
    const int cnt = e - s;
    const float inv = (cnt > 0) ? 1.0f / (float)cnt : 0.0f;
    if (grp == 0) {
      bf16x4 o;
      o[0] = (bf16)(sa[0] * inv); o[1] = (bf16)(sa[1] * inv);
      o[2] = (bf16)(sa[2] * inv); o[3] = (bf16)(sa[3] * inv);
      *(bf16x4*)(pool + (size_t)u * 64 + li * 4) = o;
    }
  }
}

// ---------------------------------------------------------------------------
extern "C" void kernel_launch(void* const* d_in, const int* in_sizes, int n_in,
                              void* d_out, int out_size, void* d_ws, size_t ws_size,
                              hipStream_t stream) {
  const float* h_user = (const float*)d_in[0];
  const float* h_tire = (const float*)d_in[1];
  const float* h_brand = (const float*)d_in[2];
  const float* h_size = (const float*)d_in[3];
  const float* specs = (const float*)d_in[4];
  const float* text = (const float*)d_in[5];
  const int* bidx = (const int*)d_in[6];
  const int* sidx = (const int*)d_in[7];
  const int* hitems = (const int*)d_in[8];
  const int* hsegs = (const int*)d_in[9];
  const float* W_tp = (const float*)d_in[10]; const float* b_tp = (const float*)d_in[11];
  const float* W_i1 = (const float*)d_in[12]; const float* b_i1 = (const float*)d_in[13];
  const float* W_i2 = (const float*)d_in[14]; const float* b_i2 = (const float*)d_in[15];
  const float* W_i3 = (const float*)d_in[16]; const float* b_i3 = (const float*)d_in[17];
  const float* W_u1 = (const float*)d_in[18]; const float* b_u1 = (const float*)d_in[19];
  const float* W_u2 = (const float*)d_in[20]; const float* b_u2 = (const float*)d_in[21];
  const float* W_u3 = (const float*)d_in[22]; const float* b_u3 = (const float*)d_in[23];

  const int U = in_sizes[0] / 128;   // 100000
  const int T = in_sizes[4] / 64;    // 100000
  const int E = in_sizes[8];         // 2000000

  char* ws = (char*)d_ws;
  size_t off = 0;
  auto alloc = [&](size_t bytes) -> char* {
    char* p = ws + off;
    off += (bytes + 255) & ~(size_t)255;
    return p;
  };
  bf16* wf_tp = (bf16*)alloc(384 * 64 * 2);
  bf16* wf_i1 = (bf16*)alloc(512 * 128 * 2);
  bf16* wf_i2 = (bf16*)alloc(128 * 128 * 2);
  bf16* wf_i3 = (bf16*)alloc(128 * 64 * 2);
  bf16* wf_u1 = (bf16*)alloc(192 * 128 * 2);
  bf16* wf_u2 = (bf16*)alloc(128 * 128 * 2);
  bf16* wf_u3 = (bf16*)alloc(128 * 64 * 2);
  bf16* tpbuf = (bf16*)alloc((size_t)T * 64 * 2);
  bf16* h1 = (bf16*)alloc((size_t)T * 128 * 2);
  bf16* h2 = (bf16*)alloc((size_t)T * 128 * 2);
  bf16* pool = (bf16*)alloc((size_t)U * 64 * 2);
  bf16* itemb = (bf16*)alloc((size_t)T * 64 * 2);
  int* bound = (int*)alloc((size_t)(U + 1) * 4);
  (void)ws_size; (void)n_in; (void)out_size;

  auto wp = [&](const float* W, bf16* dst, int K, int N) {
    int total = K * N / 8;
    wprep<<<(total + 255) / 256, 256, 0, stream>>>(W, dst, K, N);
  };
  wp(W_tp, wf_tp, 384, 64);
  wp(W_i1, wf_i1, 512, 128);
  wp(W_i2, wf_i2, 128, 128);
  wp(W_i3, wf_i3, 128, 64);
  wp(W_u1, wf_u1, 192, 128);
  wp(W_u2, wf_u2, 128, 128);
  wp(W_u3, wf_u3, 128, 64);

  // segment bounds (independent of GEMMs; overlaps fine in-stream)
  seg_bounds<<<(E + 256) / 256, 256, 0, stream>>>(hsegs, bound, E, U);

  float* out_user = (float*)d_out;
  float* out_item = out_user + (size_t)U * 64;

  const int tilesT = (T + 127) / 128;
  const int tilesU = (U + 127) / 128;

  {  // text projection: [T,384] f32 @ [384,64] -> relu -> tpbuf bf16
    GemmArgs a = {}; a.a0 = text; a.wfrag = wf_tp; a.bias = b_tp; a.out = tpbuf; a.M = T;
    gemm_k<384, 64, 0, 1, 0, 4><<<tilesT, 256, 0, stream>>>(a);
  }
  {  // item L1: concat-512 @ [512,128] -> relu -> h1 (128KB LDS, 8 waves/block)
    GemmArgs a = {}; a.a0 = h_tire; a.a1 = h_brand; a.a2 = h_size; a.a3 = specs; a.a4 = tpbuf;
    a.bidx = bidx; a.sidx = sidx; a.wfrag = wf_i1; a.bias = b_i1; a.out = h1; a.M = T;
    gemm_k<512, 128, 2, 1, 0, 8><<<(T + 255) / 256, 512, 0, stream>>>(a);
  }
  {  // item L2
    GemmArgs a = {}; a.a0 = h1; a.wfrag = wf_i2; a.bias = b_i2; a.out = h2; a.M = T;
    gemm_k<128, 128, 1, 1, 0, 4><<<tilesT, 256, 0, stream>>>(a);
  }
  {  // item L3 + l2norm -> d_out item section (f32) + bf16 copy for pooling
    GemmArgs a = {}; a.a0 = h2; a.wfrag = wf_i3; a.bias = b_i3; a.out = out_item;
    a.out2 = itemb; a.M = T;
    gemm_k<128, 64, 1, 0, 1, 4><<<tilesT, 256, 0, stream>>>(a);
  }
  // history mean-pool (bf16 gathers, precomputed bounds)
  pool_k<<<(U + 3) / 4, 256, 0, stream>>>(hitems, bound, itemb, pool, U);
  {  // user L1: concat-192 @ [192,128] -> relu -> h1
    GemmArgs a = {}; a.a0 = h_user; a.a1 = pool; a.wfrag = wf_u1; a.bias = b_u1; a.out = h1; a.M = U;
    gemm_k<192, 128, 3, 1, 0, 4><<<tilesU, 256, 0, stream>>>(a);
  }
  {  // user L2
    GemmArgs a = {}; a.a0 = h1; a.wfrag = wf_u2; a.bias = b_u2; a.out = h2; a.M = U;
    gemm_k<128, 128, 1, 1, 0, 4><<<tilesU, 256, 0, stream>>>(a);
  }
  {  // user L3 + l2norm -> d_out user section (f32)
    GemmArgs a = {}; a.a0 = h2; a.wfrag = wf_u3; a.bias = b_u3; a.out = out_user; a.M = U;
    gemm_k<128, 64, 1, 0, 1, 4><<<tilesU, 256, 0, stream>>>(a);
  }
}

// Round 3
// 227.076 us; speedup vs baseline: 2.1931x; 1.2623x over previous
//
#include <hip/hip_runtime.h>

typedef __bf16 bf16;
typedef __bf16 bf16x4 __attribute__((ext_vector_type(4)));
typedef __bf16 bf16x8 __attribute__((ext_vector_type(8)));
typedef float f32x4 __attribute__((ext_vector_type(4)));

__device__ inline float bfbits(unsigned u) { return __builtin_bit_cast(float, u); }

__device__ inline bf16x8 cvt8(const float* p) {
  const f32x4* q = (const f32x4*)p;
  f32x4 x0 = q[0];
  f32x4 x1 = q[1];
  bf16x8 a;
  a[0] = (bf16)x0[0]; a[1] = (bf16)x0[1]; a[2] = (bf16)x0[2]; a[3] = (bf16)x0[3];
  a[4] = (bf16)x1[0]; a[5] = (bf16)x1[1]; a[6] = (bf16)x1[2]; a[7] = (bf16)x1[3];
  return a;
}

// ---------------------------------------------------------------------------
// Batched weight prep: f32 W[K][N] -> MFMA B-fragment-ordered bf16.
// dst[((kt*NT+nt)*64 + lane)*8 + j] = W[map(kt*32 + (lane>>4)*8 + j)][nt*16 + (lane&15)]
// mode 1: item-L1 concat map (row<128 ? row : row+256) for [tire|specs|tproj].
// ---------------------------------------------------------------------------
struct WEnt { const float* src; bf16* dst; int K; int N; int mode; int base; };
struct WprepArgs { WEnt e[9]; int nent; int total; float* zb; };

__global__ __launch_bounds__(256) void wprep_all(WprepArgs a) {
  int idx = blockIdx.x * 256 + threadIdx.x;
  if (idx < 128) a.zb[idx] = 0.0f;
  if (idx >= a.total) return;
  int ei = 0;
  while (ei + 1 < a.nent && idx >= a.e[ei + 1].base) ++ei;
  const WEnt E = a.e[ei];
  int li = idx - E.base;
  int lane = li & 63, fi = li >> 6;
  int NT = E.N / 16;
  int kt = fi / NT, nt = fi % NT;
  int krow = kt * 32 + ((lane >> 4) << 3);
  int col = nt * 16 + (lane & 15);
  bf16* d = E.dst + (size_t)li * 8;
#pragma unroll
  for (int j = 0; j < 8; ++j) {
    int r = krow + j;
    if (E.mode == 1) r = (r < 128) ? r : r + 256;
    d[j] = (bf16)E.src[(size_t)r * E.N + col];
  }
}

// ---------------------------------------------------------------------------
// Segment bounds: bound[u] = first index i with hsegs[i] >= u, u in [0,U].
// ---------------------------------------------------------------------------
__global__ __launch_bounds__(256) void seg_bounds(const int* __restrict__ hsegs,
                                                  int* __restrict__ bound, int E, int U) {
  int e = blockIdx.x * 256 + threadIdx.x;
  if (e > E) return;
  if (e == 0) {
    int b = hsegs[0];
    for (int u = 0; u <= b; ++u) bound[u] = 0;
  } else if (e == E) {
    int a = hsegs[E - 1];
    for (int u = a + 1; u <= U; ++u) bound[u] = E;
  } else {
    int a = hsegs[e - 1], b = hsegs[e];
    for (int u = a + 1; u <= b; ++u) bound[u] = e;
  }
}

// ---------------------------------------------------------------------------
// Generic small GEMM: out[M][N] = act(A[M][K] @ W + b)
// ASRC: 0 = f32 [M][K], 1 = bf16 [M][K]
// OUTM: 0 = bf16 out, 1 = f32 + l2norm (+opt bf16 out2), 2 = f32 plain
// ---------------------------------------------------------------------------
struct GemmArgs {
  const void* a0;
  const bf16* wfrag; const float* bias;
  void* out; void* out2; int M;
};

template <int K, int ASRC>
__device__ inline bf16x8 gemm_load_a(const GemmArgs& g, int r, int kc) {
  if constexpr (ASRC == 0) {
    return cvt8((const float*)g.a0 + (size_t)r * K + kc);
  } else {
    return *(const bf16x8*)((const bf16*)g.a0 + (size_t)r * K + kc);
  }
}

template <int K, int N, int ASRC, int RELU, int OUTM, int NW>
__global__ __launch_bounds__(NW * 64) void gemm_k(GemmArgs g) {
  constexpr int KT = K / 32, NT = N / 16;
  constexpr int TROWS = NW * 32;
  __shared__ bf16 wlds[K * N];
  {
    const uint4* s = (const uint4*)g.wfrag;
    uint4* d = (uint4*)wlds;
    constexpr int CH = K * N * 2 / 16;
    for (int i = threadIdx.x; i < CH; i += NW * 64) d[i] = s[i];
  }
  __syncthreads();

  const int lane = threadIdx.x & 63;
  const int wave = threadIdx.x >> 6;
  const int kgo = (lane >> 4) << 3;
  const int ntiles = (g.M + TROWS - 1) / TROWS;

  for (int tile = blockIdx.x; tile < ntiles; tile += gridDim.x) {
    const int rowbase = tile * TROWS;
    const int rw = rowbase + wave * 16 + (lane & 15);
    const int r0 = min(rw, g.M - 1);
    const int r1 = min(rw + NW * 16, g.M - 1);

    f32x4 acc[2][NT] = {};

#pragma unroll 2
    for (int kt = 0; kt < KT; ++kt) {
      const int kc = kt * 32 + kgo;
      bf16x8 a0 = gemm_load_a<K, ASRC>(g, r0, kc);
      bf16x8 a1 = gemm_load_a<K, ASRC>(g, r1, kc);
      const bf16x8* bp = ((const bf16x8*)wlds) + kt * NT * 64 + lane;
#pragma unroll
      for (int nt = 0; nt < NT; ++nt) {
        bf16x8 b = bp[nt * 64];
        acc[0][nt] = __builtin_amdgcn_mfma_f32_16x16x32_bf16(a0, b, acc[0][nt], 0, 0, 0);
        acc[1][nt] = __builtin_amdgcn_mfma_f32_16x16x32_bf16(a1, b, acc[1][nt], 0, 0, 0);
      }
    }

    const int colbase = lane & 15;
    const int rgrp = (lane >> 4) * 4;
#pragma unroll
    for (int m = 0; m < 2; ++m) {
      const int rbase = rowbase + m * (NW * 16) + wave * 16 + rgrp;
#pragma unroll
      for (int nt = 0; nt < NT; ++nt) {
        const float bv = g.bias[colbase + nt * 16];
        f32x4 dv = acc[m][nt];
#pragma unroll
        for (int j = 0; j < 4; ++j) {
          float v = dv[j] + bv;
          if constexpr (RELU != 0) v = fmaxf(v, 0.0f);
          dv[j] = v;
        }
        acc[m][nt] = dv;
      }
      if constexpr (OUTM == 1) {
#pragma unroll
        for (int j = 0; j < 4; ++j) {
          float ssq = 0.0f;
#pragma unroll
          for (int nt = 0; nt < NT; ++nt) ssq += acc[m][nt][j] * acc[m][nt][j];
          ssq += __shfl_xor(ssq, 1);
          ssq += __shfl_xor(ssq, 2);
          ssq += __shfl_xor(ssq, 4);
          ssq += __shfl_xor(ssq, 8);
          const float scale = 1.0f / fmaxf(sqrtf(ssq), 1e-12f);
          const int r = rbase + j;
          if (r < g.M) {
            float* o = (float*)g.out + (size_t)r * N + colbase;
#pragma unroll
            for (int nt = 0; nt < NT; ++nt) o[nt * 16] = acc[m][nt][j] * scale;
            if (g.out2) {
              bf16* o2 = (bf16*)g.out2 + (size_t)r * N + colbase;
#pragma unroll
              for (int nt = 0; nt < NT; ++nt) o2[nt * 16] = (bf16)(acc[m][nt][j] * scale);
            }
          }
        }
      } else if constexpr (OUTM == 2) {
#pragma unroll
        for (int j = 0; j < 4; ++j) {
          const int r = rbase + j;
          if (r < g.M) {
            float* o = (float*)g.out + (size_t)r * N + colbase;
#pragma unroll
            for (int nt = 0; nt < NT; ++nt) o[nt * 16] = acc[m][nt][j];
          }
        }
      } else {
#pragma unroll
        for (int j = 0; j < 4; ++j) {
          const int r = rbase + j;
          if (r < g.M) {
            bf16* o = (bf16*)g.out + (size_t)r * N + colbase;
#pragma unroll
            for (int nt = 0; nt < NT; ++nt) o[nt * 16] = (bf16)acc[m][nt][j];
          }
        }
      }
    }
  }
}

// ---------------------------------------------------------------------------
// Fused 3-layer tower. One wave owns 2 groups of 16 rows through all layers.
// Layer handoff: per-wave private 16x128 LDS tile, XOR-swizzled
// (byte ^= (row&7)<<4) so ds_read_b128 A-frag reads are conflict-free.
// ASRC 2 = item concat [h_tire(128)|specs(64)|tproj(64)], K1=256
// ASRC 3 = user concat [h_user(128)|pool(64)], K1=192
// BS: add gathered brandC/sizeC (b1 pre-folded into brandC) in L1 epilogue.
// ---------------------------------------------------------------------------
struct TowerArgs {
  const void* a0; const void* a1; const void* a2;
  const int* bidx; const int* sidx;
  const float* brandC; const float* sizeC;
  const bf16* wf1; const bf16* wf2; const bf16* wf3;
  const float* b1; const float* b2; const float* b3;
  float* out; bf16* out2; int M;
};

template <int ASRC>
__device__ inline bf16x8 tower_load_a(const TowerArgs& g, int r, int kc) {
  if constexpr (ASRC == 2) {
    if (kc < 128) return cvt8((const float*)g.a0 + (size_t)r * 128 + kc);
    else if (kc < 192) return cvt8((const float*)g.a1 + (size_t)r * 64 + (kc - 128));
    else return *(const bf16x8*)((const bf16*)g.a2 + (size_t)r * 64 + (kc - 192));
  } else {
    if (kc < 128) return cvt8((const float*)g.a0 + (size_t)r * 128 + kc);
    else return *(const bf16x8*)((const bf16*)g.a1 + (size_t)r * 64 + (kc - 128));
  }
}

__device__ inline bf16x8 read_afrag(const bf16* hw, int lane, int kt) {
  const int row = lane & 15;
  const int c8 = (kt * 4 + (lane >> 4)) ^ (row & 7);
  return *(const bf16x8*)(hw + row * 128 + c8 * 8);
}

template <int K1, int ASRC, int BS>
__global__ __launch_bounds__(512, 2) void tower_k(TowerArgs g) {
  constexpr int KT1 = K1 / 32;
  constexpr int NW = 8;
  constexpr int TROWS = NW * 32;  // 256
  __shared__ bf16 lds[K1 * 128 + 128 * 128 + 128 * 64 + NW * 16 * 128];
  bf16* w1 = lds;
  bf16* w2 = lds + K1 * 128;
  bf16* w3 = w2 + 128 * 128;
  bf16* ht = w3 + 128 * 64;
  {
    const int tid = threadIdx.x;
    const uint4* s1 = (const uint4*)g.wf1; uint4* d1 = (uint4*)w1;
    for (int i = tid; i < K1 * 128 * 2 / 16; i += 512) d1[i] = s1[i];
    const uint4* s2 = (const uint4*)g.wf2; uint4* d2 = (uint4*)w2;
    for (int i = tid; i < 128 * 128 * 2 / 16; i += 512) d2[i] = s2[i];
    const uint4* s3 = (const uint4*)g.wf3; uint4* d3 = (uint4*)w3;
    for (int i = tid; i < 128 * 64 * 2 / 16; i += 512) d3[i] = s3[i];
  }
  __syncthreads();

  const int lane = threadIdx.x & 63;
  const int wave = threadIdx.x >> 6;
  const int kgo = (lane >> 4) << 3;
  const int colbase = lane & 15;
  const int r4 = (lane >> 4) * 4;
  bf16* hw = ht + wave * (16 * 128);
  const int ntiles = (g.M + TROWS - 1) / TROWS;

  for (int tile = blockIdx.x; tile < ntiles; tile += gridDim.x) {
    const int rowbase = tile * TROWS;
    const int rw = rowbase + wave * 16 + colbase;
    const int r0 = min(rw, g.M - 1);
    const int r1 = min(rw + NW * 16, g.M - 1);

    // ---- L1 ----
    f32x4 acc1[2][8] = {};
#pragma unroll 2
    for (int kt = 0; kt < KT1; ++kt) {
      const int kc = kt * 32 + kgo;
      bf16x8 a0 = tower_load_a<ASRC>(g, r0, kc);
      bf16x8 a1 = tower_load_a<ASRC>(g, r1, kc);
      const bf16x8* bp = ((const bf16x8*)w1) + kt * 8 * 64 + lane;
#pragma unroll
      for (int nt = 0; nt < 8; ++nt) {
        bf16x8 b = bp[nt * 64];
        acc1[0][nt] = __builtin_amdgcn_mfma_f32_16x16x32_bf16(a0, b, acc1[0][nt], 0, 0, 0);
        acc1[1][nt] = __builtin_amdgcn_mfma_f32_16x16x32_bf16(a1, b, acc1[1][nt], 0, 0, 0);
      }
    }

    f32x4 acc3[2][4] = {};
#pragma unroll
    for (int m = 0; m < 2; ++m) {
      const int rbase = rowbase + m * (NW * 16) + wave * 16 + r4;
      // L1 epilogue -> stage bf16 h1 tile (per-wave, swizzled)
#pragma unroll
      for (int j = 0; j < 4; ++j) {
        const int row = r4 + j;
        const float* bc = nullptr; const float* sc = nullptr;
        if constexpr (BS != 0) {
          const int rr = min(rbase + j, g.M - 1);
          bc = g.brandC + (size_t)g.bidx[rr] * 128;
          sc = g.sizeC + (size_t)g.sidx[rr] * 128;
        }
#pragma unroll
        for (int nt = 0; nt < 8; ++nt) {
          const int col = colbase + nt * 16;
          float v = acc1[m][nt][j];
          if constexpr (BS != 0) v += bc[col] + sc[col];
          else v += g.b1[col];
          v = fmaxf(v, 0.0f);
          const int c8 = (col >> 3) ^ (row & 7);
          hw[row * 128 + c8 * 8 + (col & 7)] = (bf16)v;
        }
      }
      // ---- L2 ----
      f32x4 acc2[8] = {};
#pragma unroll
      for (int kt = 0; kt < 4; ++kt) {
        bf16x8 a = read_afrag(hw, lane, kt);
        const bf16x8* bp = ((const bf16x8*)w2) + kt * 8 * 64 + lane;
#pragma unroll
        for (int nt = 0; nt < 8; ++nt)
          acc2[nt] = __builtin_amdgcn_mfma_f32_16x16x32_bf16(a, bp[nt * 64], acc2[nt], 0, 0, 0);
      }
      // L2 epilogue -> stage h2 tile
#pragma unroll
      for (int j = 0; j < 4; ++j) {
        const int row = r4 + j;
#pragma unroll
        for (int nt = 0; nt < 8; ++nt) {
          const int col = colbase + nt * 16;
          float v = fmaxf(acc2[nt][j] + g.b2[col], 0.0f);
          const int c8 = (col >> 3) ^ (row & 7);
          hw[row * 128 + c8 * 8 + (col & 7)] = (bf16)v;
        }
      }
      // ---- L3 ----
#pragma unroll
      for (int kt = 0; kt < 4; ++kt) {
        bf16x8 a = read_afrag(hw, lane, kt);
        const bf16x8* bp = ((const bf16x8*)w3) + kt * 4 * 64 + lane;
#pragma unroll
        for (int nt = 0; nt < 4; ++nt)
          acc3[m][nt] = __builtin_amdgcn_mfma_f32_16x16x32_bf16(a, bp[nt * 64], acc3[m][nt], 0, 0, 0);
      }
    }

    // ---- final epilogue: bias + l2norm + store ----
#pragma unroll
    for (int m = 0; m < 2; ++m) {
      const int rbase = rowbase + m * (NW * 16) + wave * 16 + r4;
#pragma unroll
      for (int j = 0; j < 4; ++j) {
        float vv[4];
        float ssq = 0.0f;
#pragma unroll
        for (int nt = 0; nt < 4; ++nt) {
          float v = acc3[m][nt][j] + g.b3[colbase + nt * 16];
          vv[nt] = v;
          ssq += v * v;
        }
        ssq += __shfl_xor(ssq, 1);
        ssq += __shfl_xor(ssq, 2);
        ssq += __shfl_xor(ssq, 4);
        ssq += __shfl_xor(ssq, 8);
        const float scale = 1.0f / fmaxf(sqrtf(ssq), 1e-12f);
        const int r = rbase + j;
        if (r < g.M) {
          float* o = g.out + (size_t)r * 64 + colbase;
#pragma unroll
          for (int nt = 0; nt < 4; ++nt) o[nt * 16] = vv[nt] * scale;
          if (g.out2) {
            bf16* o2 = g.out2 + (size_t)r * 64 + colbase;
#pragma unroll
            for (int nt = 0; nt < 4; ++nt) o2[nt * 16] = (bf16)(vv[nt] * scale);
          }
        }
      }
    }
  }
}

// ---------------------------------------------------------------------------
// Segment-mean pooling (precomputed bounds, bf16 item rows).
// ---------------------------------------------------------------------------
__global__ __launch_bounds__(256) void pool_k(const int* __restrict__ hitems,
                                              const int* __restrict__ bound,
                                              const bf16* __restrict__ itemb,
                                              bf16* __restrict__ pool, int U) {
  const int lane = threadIdx.x & 63;
  const int wid = blockIdx.x * 4 + (threadIdx.x >> 6);
  const int stride = gridDim.x * 4;
  const int grp = lane >> 4, li = lane & 15;
  for (int u = wid; u < U; u += stride) {
    const int s = bound[u], e = bound[u + 1];
    f32x4 sa = {0.f, 0.f, 0.f, 0.f}, sb = {0.f, 0.f, 0.f, 0.f};
    int i = s + grp;
    for (; i + 4 < e; i += 8) {
      int it0 = hitems[i];
      int it1 = hitems[i + 4];
      uint2 r0 = *(const uint2*)(itemb + (size_t)it0 * 64 + li * 4);
      uint2 r1 = *(const uint2*)(itemb + (size_t)it1 * 64 + li * 4);
      sa[0] += bfbits(r0.x << 16);      sa[1] += bfbits(r0.x & 0xffff0000u);
      sa[2] += bfbits(r0.y << 16);      sa[3] += bfbits(r0.y & 0xffff0000u);
      sb[0] += bfbits(r1.x << 16);      sb[1] += bfbits(r1.x & 0xffff0000u);
      sb[2] += bfbits(r1.y << 16);      sb[3] += bfbits(r1.y & 0xffff0000u);
    }
    if (i < e) {
      int it0 = hitems[i];
      uint2 r0 = *(const uint2*)(itemb + (size_t)it0 * 64 + li * 4);
      sa[0] += bfbits(r0.x << 16);      sa[1] += bfbits(r0.x & 0xffff0000u);
      sa[2] += bfbits(r0.y << 16);      sa[3] += bfbits(r0.y & 0xffff0000u);
    }
#pragma unroll
    for (int c = 0; c < 4; ++c) sa[c] += sb[c];
#pragma unroll
    for (int c = 0; c < 4; ++c) {
      sa[c] += __shfl_xor(sa[c], 16);
      sa[c] += __shfl_xor(sa[c], 32);
    }
    const int cnt = e - s;
    const float inv = (cnt > 0) ? 1.0f / (float)cnt : 0.0f;
    if (grp == 0) {
      bf16x4 o;
      o[0] = (bf16)(sa[0] * inv); o[1] = (bf16)(sa[1] * inv);
      o[2] = (bf16)(sa[2] * inv); o[3] = (bf16)(sa[3] * inv);
      *(bf16x4*)(pool + (size_t)u * 64 + li * 4) = o;
    }
  }
}

// ---------------------------------------------------------------------------
extern "C" void kernel_launch(void* const* d_in, const int* in_sizes, int n_in,
                              void* d_out, int out_size, void* d_ws, size_t ws_size,
                              hipStream_t stream) {
  const float* h_user = (const float*)d_in[0];
  const float* h_tire = (const float*)d_in[1];
  const float* h_brand = (const float*)d_in[2];
  const float* h_size = (const float*)d_in[3];
  const float* specs = (const float*)d_in[4];
  const float* text = (const float*)d_in[5];
  const int* bidx = (const int*)d_in[6];
  const int* sidx = (const int*)d_in[7];
  const int* hitems = (const int*)d_in[8];
  const int* hsegs = (const int*)d_in[9];
  const float* W_tp = (const float*)d_in[10]; const float* b_tp = (const float*)d_in[11];
  const float* W_i1 = (const float*)d_in[12]; const float* b_i1 = (const float*)d_in[13];
  const float* W_i2 = (const float*)d_in[14]; const float* b_i2 = (const float*)d_in[15];
  const float* W_i3 = (const float*)d_in[16]; const float* b_i3 = (const float*)d_in[17];
  const float* W_u1 = (const float*)d_in[18]; const float* b_u1 = (const float*)d_in[19];
  const float* W_u2 = (const float*)d_in[20]; const float* b_u2 = (const float*)d_in[21];
  const float* W_u3 = (const float*)d_in[22]; const float* b_u3 = (const float*)d_in[23];

  const int U = in_sizes[0] / 128;   // 100000
  const int T = in_sizes[4] / 64;    // 100000
  const int E = in_sizes[8];         // 2000000

  char* ws = (char*)d_ws;
  size_t off = 0;
  auto alloc = [&](size_t bytes) -> char* {
    char* p = ws + off;
    off += (bytes + 255) & ~(size_t)255;
    return p;
  };
  bf16* wf_tp  = (bf16*)alloc(384 * 64 * 2);
  bf16* wf_i1a = (bf16*)alloc(256 * 128 * 2);
  bf16* wf_ib  = (bf16*)alloc(128 * 128 * 2);
  bf16* wf_is  = (bf16*)alloc(128 * 128 * 2);
  bf16* wf_i2  = (bf16*)alloc(128 * 128 * 2);
  bf16* wf_i3  = (bf16*)alloc(128 * 64 * 2);
  bf16* wf_u1  = (bf16*)alloc(192 * 128 * 2);
  bf16* wf_u2  = (bf16*)alloc(128 * 128 * 2);
  bf16* wf_u3  = (bf16*)alloc(128 * 64 * 2);
  float* zb    = (float*)alloc(128 * 4);
  float* brandC = (float*)alloc(100 * 128 * 4);
  float* sizeC  = (float*)alloc(500 * 128 * 4);
  bf16* tpbuf = (bf16*)alloc((size_t)T * 64 * 2);
  bf16* pool  = (bf16*)alloc((size_t)U * 64 * 2);
  bf16* itemb = (bf16*)alloc((size_t)T * 64 * 2);
  int* bound  = (int*)alloc((size_t)(U + 1) * 4);
  (void)ws_size; (void)n_in; (void)out_size;

  // --- batched weight prep ---
  WprepArgs wa = {};
  auto addent = [&](int i, const float* src, bf16* dst, int K, int N, int mode, int& run) {
    wa.e[i] = {src, dst, K, N, mode, run};
    run += (K / 32) * (N / 16) * 64;
  };
  int run = 0;
  addent(0, W_tp, wf_tp, 384, 64, 0, run);
  addent(1, W_i1, wf_i1a, 256, 128, 1, run);            // [tire|specs|tproj] rows
  addent(2, W_i1 + 128 * 128, wf_ib, 128, 128, 0, run); // brand rows
  addent(3, W_i1 + 256 * 128, wf_is, 128, 128, 0, run); // size rows
  addent(4, W_i2, wf_i2, 128, 128, 0, run);
  addent(5, W_i3, wf_i3, 128, 64, 0, run);
  addent(6, W_u1, wf_u1, 192, 128, 0, run);
  addent(7, W_u2, wf_u2, 128, 128, 0, run);
  addent(8, W_u3, wf_u3, 128, 64, 0, run);
  wa.nent = 9; wa.total = run; wa.zb = zb;
  wprep_all<<<(run + 255) / 256, 256, 0, stream>>>(wa);

  seg_bounds<<<(E + 256) / 256, 256, 0, stream>>>(hsegs, bound, E, U);

  {  // brandC[100][128] = h_brand @ W_i1[128:256] + b_i1   (bias folded here)
    GemmArgs a = {}; a.a0 = h_brand; a.wfrag = wf_ib; a.bias = b_i1; a.out = brandC; a.M = 100;
    gemm_k<128, 128, 0, 0, 2, 4><<<1, 256, 0, stream>>>(a);
  }
  {  // sizeC[500][128] = h_size @ W_i1[256:384]   (zero bias)
    GemmArgs a = {}; a.a0 = h_size; a.wfrag = wf_is; a.bias = zb; a.out = sizeC; a.M = 500;
    gemm_k<128, 128, 0, 0, 2, 4><<<4, 256, 0, stream>>>(a);
  }
  {  // text projection: [T,384] f32 @ [384,64] -> relu -> tpbuf bf16
    GemmArgs a = {}; a.a0 = text; a.wfrag = wf_tp; a.bias = b_tp; a.out = tpbuf; a.M = T;
    gemm_k<384, 64, 0, 1, 0, 4><<<(T + 127) / 128, 256, 0, stream>>>(a);
  }

  float* out_user = (float*)d_out;
  float* out_item = out_user + (size_t)U * 64;

  {  // fused item tower
    TowerArgs a = {};
    a.a0 = h_tire; a.a1 = specs; a.a2 = tpbuf;
    a.bidx = bidx; a.sidx = sidx; a.brandC = brandC; a.sizeC = sizeC;
    a.wf1 = wf_i1a; a.wf2 = wf_i2; a.wf3 = wf_i3;
    a.b1 = zb; a.b2 = b_i2; a.b3 = b_i3;
    a.out = out_item; a.out2 = itemb; a.M = T;
    tower_k<256, 2, 1><<<(T + 255) / 256, 512, 0, stream>>>(a);
  }

  pool_k<<<(U + 3) / 4, 256, 0, stream>>>(hitems, bound, itemb, pool, U);

  {  // fused user tower
    TowerArgs a = {};
    a.a0 = h_user; a.a1 = pool;
    a.wf1 = wf_u1; a.wf2 = wf_u2; a.wf3 = wf_u3;
    a.b1 = b_u1; a.b2 = b_u2; a.b3 = b_u3;
    a.out = out_user; a.out2 = nullptr; a.M = U;
    tower_k<192, 3, 0><<<(U + 255) / 256, 512, 0, stream>>>(a);
  }
}